// Round 1
// baseline (473243.018 us; speedup 1.0000x reference)
//
#include <hip/hip_runtime.h>

#define BATCH 16384
#define LOOK 30
#define HID 1024
#define DEPTH 10
#define NSTEPS 16
#define ALPHA 0.3f

__device__ __forceinline__ float leaky(float x) { return x > 0.f ? x : ALPHA * x; }

// ---------------------------------------------------------------------------
// Kernel A: z = y + sum_j c_j * k_j  (c_j already include h), then
//           H1 = leaky(z @ W1 + b1)   [BATCH x 30] -> [BATCH x 1024]
// grid: (1024/256, BATCH/64), block: 256
// ---------------------------------------------------------------------------
__global__ __launch_bounds__(256) void k_layer1(
    const float* __restrict__ y,
    const float* __restrict__ k1, const float* __restrict__ k2,
    const float* __restrict__ k3, const float* __restrict__ k4,
    const float* __restrict__ k5,
    float c1, float c2, float c3, float c4, float c5,
    const float* __restrict__ W1d, const float* __restrict__ b1d,
    float* __restrict__ H1) {
  __shared__ float zs[64][32];
  const int row0 = blockIdx.y * 64;
  const int col0 = blockIdx.x * 256;

  for (int i = threadIdx.x; i < 64 * 32; i += 256) {
    int r = i >> 5, c = i & 31;
    float v = 0.f;
    if (c < LOOK) {
      size_t idx = (size_t)(row0 + r) * LOOK + c;
      v = y[idx] + c1 * k1[idx] + c2 * k2[idx] + c3 * k3[idx] + c4 * k4[idx] +
          c5 * k5[idx];
    }
    zs[r][c] = v;
  }
  __syncthreads();

  const int c = col0 + threadIdx.x;
  float w[32];
#pragma unroll
  for (int k = 0; k < LOOK; ++k) w[k] = W1d[(size_t)k * HID + c];
  w[30] = 0.f;
  w[31] = 0.f;
  const float b = b1d[c];

  for (int r = 0; r < 64; ++r) {
    float acc = b;
#pragma unroll
    for (int k4i = 0; k4i < 8; ++k4i) {
      float4 zv = *(const float4*)&zs[r][k4i * 4];
      acc += zv.x * w[k4i * 4 + 0] + zv.y * w[k4i * 4 + 1] +
             zv.z * w[k4i * 4 + 2] + zv.w * w[k4i * 4 + 3];
    }
    H1[(size_t)(row0 + r) * HID + c] = leaky(acc);
  }
}

// ---------------------------------------------------------------------------
// Kernel B: H2 = leaky(H1 @ W2 + b2)   [BATCH x 1024] @ [1024 x 1024]
// 128x128 tile, BK=8, 8x8 microtile, 256 threads.
// grid: (1024/128, BATCH/128)
// ---------------------------------------------------------------------------
__global__ __launch_bounds__(256) void k_layer2(
    const float* __restrict__ H1, const float* __restrict__ W2d,
    const float* __restrict__ b2d, float* __restrict__ H2) {
  __shared__ float As[8][128];
  __shared__ float Bs[8][128];
  const int tx = threadIdx.x & 15;
  const int ty = threadIdx.x >> 4;
  const int row0 = blockIdx.y * 128;
  const int col0 = blockIdx.x * 128;

  float acc[8][8] = {};

  const int am = threadIdx.x >> 1;        // 0..127
  const int ak = (threadIdx.x & 1) * 4;   // 0 or 4
  const int kb = threadIdx.x >> 5;        // 0..7
  const int nb = (threadIdx.x & 31) * 4;  // 0..124

  for (int k0 = 0; k0 < HID; k0 += 8) {
    float4 av = *(const float4*)&H1[(size_t)(row0 + am) * HID + k0 + ak];
    float4 bv = *(const float4*)&W2d[(size_t)(k0 + kb) * HID + col0 + nb];
    __syncthreads();  // previous iteration's reads complete
    As[ak + 0][am] = av.x;
    As[ak + 1][am] = av.y;
    As[ak + 2][am] = av.z;
    As[ak + 3][am] = av.w;
    *(float4*)&Bs[kb][nb] = bv;
    __syncthreads();
#pragma unroll
    for (int kk = 0; kk < 8; ++kk) {
      float4 a0 = *(const float4*)&As[kk][ty * 8];
      float4 a1 = *(const float4*)&As[kk][ty * 8 + 4];
      float4 b0 = *(const float4*)&Bs[kk][tx * 8];
      float4 b1 = *(const float4*)&Bs[kk][tx * 8 + 4];
      float ar[8] = {a0.x, a0.y, a0.z, a0.w, a1.x, a1.y, a1.z, a1.w};
      float br[8] = {b0.x, b0.y, b0.z, b0.w, b1.x, b1.y, b1.z, b1.w};
#pragma unroll
      for (int i = 0; i < 8; ++i)
#pragma unroll
        for (int j = 0; j < 8; ++j) acc[i][j] += ar[i] * br[j];
    }
  }

#pragma unroll
  for (int i = 0; i < 8; ++i) {
    const int r = row0 + ty * 8 + i;
#pragma unroll
    for (int j = 0; j < 8; ++j) {
      const int c = col0 + tx * 8 + j;
      H2[(size_t)r * HID + c] = leaky(acc[i][j] + b2d[c]);
    }
  }
}

// ---------------------------------------------------------------------------
// Kernel C: k_out = H2 @ W3 + b3   [BATCH x 1024] @ [1024 x 30]
// If combine: y += hb1*k1 + ... + hb5*k5 + hb6*k_out  (DoPri5 b-row)
// grid: BATCH/64 blocks, 256 threads.
// ---------------------------------------------------------------------------
__global__ __launch_bounds__(256) void k_layer3(
    const float* __restrict__ H2, const float* __restrict__ W3d,
    const float* __restrict__ b3d, float* __restrict__ kout, int combine,
    float* __restrict__ y,
    const float* __restrict__ k1, const float* __restrict__ k2,
    const float* __restrict__ k3, const float* __restrict__ k4,
    const float* __restrict__ k5,
    float hb1, float hb2, float hb3, float hb4, float hb5, float hb6) {
  __shared__ float H2s[64][68];
  __shared__ float W3Ts[32][68];
  const int row0 = blockIdx.x * 64;
  const int c16 = threadIdx.x & 15;
  const int rgrp = threadIdx.x >> 4;

  float acc[4][2] = {};

  for (int kc = 0; kc < HID; kc += 64) {
    __syncthreads();  // previous chunk reads complete
    {
      int r = threadIdx.x >> 2;
      int ks = (threadIdx.x & 3) * 16;
      const float* src = &H2[(size_t)(row0 + r) * HID + kc + ks];
      float4 v0 = ((const float4*)src)[0];
      float4 v1 = ((const float4*)src)[1];
      float4 v2 = ((const float4*)src)[2];
      float4 v3 = ((const float4*)src)[3];
      *(float4*)&H2s[r][ks + 0] = v0;
      *(float4*)&H2s[r][ks + 4] = v1;
      *(float4*)&H2s[r][ks + 8] = v2;
      *(float4*)&H2s[r][ks + 12] = v3;
    }
    for (int i = threadIdx.x; i < 32 * 64; i += 256) {
      int cc = i & 31, kk = i >> 5;
      W3Ts[cc][kk] = (cc < LOOK) ? W3d[(size_t)(kc + kk) * LOOK + cc] : 0.f;
    }
    __syncthreads();
#pragma unroll
    for (int k4i = 0; k4i < 16; ++k4i) {
      float4 w0 = *(const float4*)&W3Ts[c16][k4i * 4];
      float4 w1 = *(const float4*)&W3Ts[c16 + 16][k4i * 4];
#pragma unroll
      for (int i = 0; i < 4; ++i) {
        float4 hv = *(const float4*)&H2s[rgrp * 4 + i][k4i * 4];
        acc[i][0] += hv.x * w0.x + hv.y * w0.y + hv.z * w0.z + hv.w * w0.w;
        acc[i][1] += hv.x * w1.x + hv.y * w1.y + hv.z * w1.z + hv.w * w1.w;
      }
    }
  }

#pragma unroll
  for (int i = 0; i < 4; ++i) {
    const int r = row0 + rgrp * 4 + i;
#pragma unroll
    for (int jj = 0; jj < 2; ++jj) {
      const int c = c16 + jj * 16;
      if (c < LOOK) {
        const size_t idx = (size_t)r * LOOK + c;
        const float kv = acc[i][jj] + b3d[c];
        kout[idx] = kv;
        if (combine) {
          y[idx] = y[idx] + hb1 * k1[idx] + hb2 * k2[idx] + hb3 * k3[idx] +
                   hb4 * k4[idx] + hb5 * k5[idx] + hb6 * kv;
        }
      }
    }
  }
}

// ---------------------------------------------------------------------------
// Final readout: out[r] = dot(y[r], Wf) + bf
// ---------------------------------------------------------------------------
__global__ __launch_bounds__(256) void k_readout(const float* __restrict__ y,
                                                 const float* __restrict__ Wf,
                                                 const float* __restrict__ bf,
                                                 float* __restrict__ out) {
  const int r = blockIdx.x * blockDim.x + threadIdx.x;
  if (r >= BATCH) return;
  float acc = bf[0];
#pragma unroll
  for (int c = 0; c < LOOK; ++c) acc += y[(size_t)r * LOOK + c] * Wf[c];
  out[r] = acc;
}

// ---------------------------------------------------------------------------
extern "C" void kernel_launch(void* const* d_in, const int* in_sizes, int n_in,
                              void* d_out, int out_size, void* d_ws,
                              size_t ws_size, hipStream_t stream) {
  const float* y0 = (const float*)d_in[0];
  const float* W1 = (const float*)d_in[1];
  const float* b1 = (const float*)d_in[2];
  const float* W2 = (const float*)d_in[3];
  const float* b2 = (const float*)d_in[4];
  const float* W3 = (const float*)d_in[5];
  const float* b3 = (const float*)d_in[6];
  const float* Wf = (const float*)d_in[7];
  const float* bf = (const float*)d_in[8];
  float* out = (float*)d_out;

  float* ws = (float*)d_ws;
  const size_t NY = (size_t)BATCH * LOOK;
  float* y = ws;
  float* kk[6];
  for (int i = 0; i < 6; ++i) kk[i] = ws + NY * (1 + i);
  float* H1 = ws + NY * 7;
  float* H2 = H1 + (size_t)BATCH * HID;

  hipMemcpyAsync(y, y0, NY * sizeof(float), hipMemcpyDeviceToDevice, stream);

  const double hh = 1.0 / 16.0;  // fixed step, NUM_STEPS = 16
  static const double A[6][5] = {
      {0, 0, 0, 0, 0},
      {1.0 / 5, 0, 0, 0, 0},
      {3.0 / 40, 9.0 / 40, 0, 0, 0},
      {44.0 / 45, -56.0 / 15, 32.0 / 9, 0, 0},
      {19372.0 / 6561, -25360.0 / 2187, 64448.0 / 6561, -212.0 / 729, 0},
      {9017.0 / 3168, -355.0 / 33, 46732.0 / 5247, 49.0 / 176,
       -5103.0 / 18656},
  };
  static const double Bb[6] = {35.0 / 384,  0,            500.0 / 1113,
                               125.0 / 192, -2187.0 / 6784, 11.0 / 84};

  const float hb1 = (float)(hh * Bb[0]);
  const float hb2 = (float)(hh * Bb[1]);
  const float hb3 = (float)(hh * Bb[2]);
  const float hb4 = (float)(hh * Bb[3]);
  const float hb5 = (float)(hh * Bb[4]);
  const float hb6 = (float)(hh * Bb[5]);

  for (int d = 0; d < DEPTH; ++d) {
    const float* W1d = W1 + (size_t)d * LOOK * HID;
    const float* b1d = b1 + (size_t)d * HID;
    const float* W2d = W2 + (size_t)d * HID * HID;
    const float* b2d = b2 + (size_t)d * HID;
    const float* W3d = W3 + (size_t)d * HID * LOOK;
    const float* b3d = b3 + (size_t)d * LOOK;

    for (int s = 0; s < NSTEPS; ++s) {
      for (int st = 0; st < 6; ++st) {
        const float c1 = (float)(hh * A[st][0]);
        const float c2 = (float)(hh * A[st][1]);
        const float c3 = (float)(hh * A[st][2]);
        const float c4 = (float)(hh * A[st][3]);
        const float c5 = (float)(hh * A[st][4]);
        k_layer1<<<dim3(HID / 256, BATCH / 64), 256, 0, stream>>>(
            y, kk[0], kk[1], kk[2], kk[3], kk[4], c1, c2, c3, c4, c5, W1d, b1d,
            H1);
        k_layer2<<<dim3(HID / 128, BATCH / 128), 256, 0, stream>>>(H1, W2d,
                                                                   b2d, H2);
        const int comb = (st == 5) ? 1 : 0;
        k_layer3<<<dim3(BATCH / 64), 256, 0, stream>>>(
            H2, W3d, b3d, kk[st], comb, y, kk[0], kk[1], kk[2], kk[3], kk[4],
            hb1, hb2, hb3, hb4, hb5, hb6);
      }
    }
  }

  k_readout<<<dim3(BATCH / 256), 256, 0, stream>>>(y, Wf, bf, out);
}

// Round 2
// 194562.878 us; speedup vs baseline: 2.4323x; 2.4323x over previous
//
#include <hip/hip_runtime.h>

#define BATCH 16384
#define LOOK 30
#define HID 1024
#define DEPTH 10
#define NSTEPS 16
#define ALPHA 0.3f

typedef short bf16x8 __attribute__((ext_vector_type(8)));
typedef float f32x4 __attribute__((ext_vector_type(4)));

__device__ __forceinline__ float leaky(float x) { return x > 0.f ? x : ALPHA * x; }

__device__ __forceinline__ unsigned short f2bf(float x) {
  unsigned u = __builtin_bit_cast(unsigned, x);
  unsigned r = u + 0x7FFFu + ((u >> 16) & 1u);
  return (unsigned short)(r >> 16);
}
__device__ __forceinline__ float bf2f(unsigned short b) {
  return __builtin_bit_cast(float, (unsigned)b << 16);
}

#define GLD_LDS16(g, l)                                        \
  __builtin_amdgcn_global_load_lds(                            \
      (const __attribute__((address_space(1))) void*)(g),      \
      (__attribute__((address_space(3))) void*)(l), 16, 0, 0)

// ---------------------------------------------------------------------------
// Once per depth: W2[k][n] fp32 -> W2T[n][k] split into hi/lo bf16.
// grid (16,16), block 256. 64x64 tiles via LDS.
// ---------------------------------------------------------------------------
__global__ __launch_bounds__(256) void k_w2split(const float* __restrict__ W2d,
                                                 short* __restrict__ W2Th,
                                                 short* __restrict__ W2Tl) {
  __shared__ float t[64][65];
  const int kb = blockIdx.x * 64;
  const int nb = blockIdx.y * 64;
  for (int i = threadIdx.x; i < 4096; i += 256) {
    int r = i >> 6, c = i & 63;  // r = k, c = n
    t[r][c] = W2d[(size_t)(kb + r) * HID + nb + c];
  }
  __syncthreads();
  for (int i = threadIdx.x; i < 4096; i += 256) {
    int r = i >> 6, c = i & 63;  // r = n, c = k
    float v = t[c][r];
    unsigned short hi = f2bf(v);
    unsigned short lo = f2bf(v - bf2f(hi));
    W2Th[(size_t)(nb + r) * HID + kb + c] = (short)hi;
    W2Tl[(size_t)(nb + r) * HID + kb + c] = (short)lo;
  }
}

// ---------------------------------------------------------------------------
// Kernel A: z = y + sum_j c_j k_j ; H1 = leaky(z @ W1 + b1), emitted as
// hi/lo bf16 split. grid (HID/256, BATCH/64), block 256.
// ---------------------------------------------------------------------------
__global__ __launch_bounds__(256) void k_layer1(
    const float* __restrict__ y, const float* __restrict__ k1,
    const float* __restrict__ k2, const float* __restrict__ k3,
    const float* __restrict__ k4, const float* __restrict__ k5, float c1,
    float c2, float c3, float c4, float c5, const float* __restrict__ W1d,
    const float* __restrict__ b1d, short* __restrict__ H1h,
    short* __restrict__ H1l) {
  __shared__ float zs[64][32];
  const int row0 = blockIdx.y * 64;
  const int col0 = blockIdx.x * 256;

  for (int i = threadIdx.x; i < 64 * 32; i += 256) {
    int r = i >> 5, c = i & 31;
    float v = 0.f;
    if (c < LOOK) {
      size_t idx = (size_t)(row0 + r) * LOOK + c;
      v = y[idx] + c1 * k1[idx] + c2 * k2[idx] + c3 * k3[idx] + c4 * k4[idx] +
          c5 * k5[idx];
    }
    zs[r][c] = v;
  }
  __syncthreads();

  const int c = col0 + threadIdx.x;
  float w[32];
#pragma unroll
  for (int k = 0; k < LOOK; ++k) w[k] = W1d[(size_t)k * HID + c];
  w[30] = 0.f;
  w[31] = 0.f;
  const float b = b1d[c];

  for (int r = 0; r < 64; ++r) {
    float acc = b;
#pragma unroll
    for (int k4i = 0; k4i < 8; ++k4i) {
      float4 zv = *(const float4*)&zs[r][k4i * 4];
      acc += zv.x * w[k4i * 4 + 0] + zv.y * w[k4i * 4 + 1] +
             zv.z * w[k4i * 4 + 2] + zv.w * w[k4i * 4 + 3];
    }
    float h = leaky(acc);
    unsigned short hi = f2bf(h);
    unsigned short lo = f2bf(h - bf2f(hi));
    const size_t o = (size_t)(row0 + r) * HID + c;
    H1h[o] = (short)hi;
    H1l[o] = (short)lo;
  }
}

// ---------------------------------------------------------------------------
// Kernel B (MFMA): H2 = leaky(H1 @ W2 + b2) with split-bf16.
// 128x128 tile, BK=32, 4 waves, m97 structure (global_load_lds w16, 2 barriers).
// grid (BATCH/128, HID/128) -> x = row block (so same-row col blocks share XCD).
// ---------------------------------------------------------------------------
__global__ __launch_bounds__(256) void k_mid(
    const short* __restrict__ H1h, const short* __restrict__ H1l,
    const short* __restrict__ W2Th, const short* __restrict__ W2Tl,
    const float* __restrict__ b2d, float* __restrict__ H2) {
  __shared__ short Ah[128 * 32];
  __shared__ short Al[128 * 32];
  __shared__ short Bh[128 * 32];
  __shared__ short Bl[128 * 32];

  const int tid = threadIdx.x;
  const int lane = tid & 63;
  const int wave = tid >> 6;
  const int row0 = blockIdx.x * 128;
  const int n0 = blockIdx.y * 128;
  const int wm = (wave >> 1) * 64;
  const int wn = (wave & 1) * 64;

  // staging: wave writes 2 chunks of 1KB per tile; lane element o bytes
  const int o0 = (wave * 2 + 0) * 1024 + lane * 16;
  const int o1 = (wave * 2 + 1) * 1024 + lane * 16;
  const int r0s = o0 >> 6, i0s = o0 & 63;  // row in tile, byte-in-row
  const int r1s = o1 >> 6, i1s = o1 & 63;

  const char* gAh = (const char*)(H1h + (size_t)row0 * HID);
  const char* gAl = (const char*)(H1l + (size_t)row0 * HID);
  const char* gBh = (const char*)(W2Th + (size_t)n0 * HID);
  const char* gBl = (const char*)(W2Tl + (size_t)n0 * HID);
  const size_t rs = (size_t)HID * 2;  // global row stride bytes

  short* ldsA0h = &Ah[(wave * 2 + 0) * 512];
  short* ldsA1h = &Ah[(wave * 2 + 1) * 512];
  short* ldsA0l = &Al[(wave * 2 + 0) * 512];
  short* ldsA1l = &Al[(wave * 2 + 1) * 512];
  short* ldsB0h = &Bh[(wave * 2 + 0) * 512];
  short* ldsB1h = &Bh[(wave * 2 + 1) * 512];
  short* ldsB0l = &Bl[(wave * 2 + 0) * 512];
  short* ldsB1l = &Bl[(wave * 2 + 1) * 512];

  f32x4 acc[4][4];
#pragma unroll
  for (int i = 0; i < 4; ++i)
#pragma unroll
    for (int j = 0; j < 4; ++j) acc[i][j] = (f32x4){0.f, 0.f, 0.f, 0.f};

  const int arow = wm + (lane & 15);
  const int brow = wn + (lane & 15);
  const int kh = (lane >> 4) * 8;  // k offset in shorts

  for (int k0 = 0; k0 < HID; k0 += 32) {
    const size_t gk = (size_t)k0 * 2;
    GLD_LDS16(gAh + (size_t)r0s * rs + gk + i0s, ldsA0h);
    GLD_LDS16(gAh + (size_t)r1s * rs + gk + i1s, ldsA1h);
    GLD_LDS16(gAl + (size_t)r0s * rs + gk + i0s, ldsA0l);
    GLD_LDS16(gAl + (size_t)r1s * rs + gk + i1s, ldsA1l);
    GLD_LDS16(gBh + (size_t)r0s * rs + gk + i0s, ldsB0h);
    GLD_LDS16(gBh + (size_t)r1s * rs + gk + i1s, ldsB1h);
    GLD_LDS16(gBl + (size_t)r0s * rs + gk + i0s, ldsB0l);
    GLD_LDS16(gBl + (size_t)r1s * rs + gk + i1s, ldsB1l);
    __syncthreads();

    bf16x8 ah[4], al[4], bh[4], bl[4];
#pragma unroll
    for (int i = 0; i < 4; ++i) {
      ah[i] = *(const bf16x8*)&Ah[(arow + i * 16) * 32 + kh];
      al[i] = *(const bf16x8*)&Al[(arow + i * 16) * 32 + kh];
    }
#pragma unroll
    for (int j = 0; j < 4; ++j) {
      bh[j] = *(const bf16x8*)&Bh[(brow + j * 16) * 32 + kh];
      bl[j] = *(const bf16x8*)&Bl[(brow + j * 16) * 32 + kh];
    }
#pragma unroll
    for (int i = 0; i < 4; ++i)
#pragma unroll
      for (int j = 0; j < 4; ++j) {
        acc[i][j] =
            __builtin_amdgcn_mfma_f32_16x16x32_bf16(ah[i], bh[j], acc[i][j], 0, 0, 0);
        acc[i][j] =
            __builtin_amdgcn_mfma_f32_16x16x32_bf16(ah[i], bl[j], acc[i][j], 0, 0, 0);
        acc[i][j] =
            __builtin_amdgcn_mfma_f32_16x16x32_bf16(al[i], bh[j], acc[i][j], 0, 0, 0);
      }
    __syncthreads();
  }

  // epilogue: C/D layout col = lane&15, row = (lane>>4)*4 + reg
  const int crow = (lane >> 4) * 4;
  const int ccol = lane & 15;
#pragma unroll
  for (int j = 0; j < 4; ++j) {
    const int col = n0 + wn + j * 16 + ccol;
    const float b2 = b2d[col];
#pragma unroll
    for (int i = 0; i < 4; ++i) {
      const int rbase = row0 + wm + i * 16 + crow;
#pragma unroll
      for (int r = 0; r < 4; ++r) {
        H2[(size_t)(rbase + r) * HID + col] = leaky(acc[i][j][r] + b2);
      }
    }
  }
}

// ---------------------------------------------------------------------------
// Kernel C: k_out = H2 @ W3 + b3 ; if combine: y += sum hb_j k_j (no kout write)
// grid (BATCH/64), block 256.
// ---------------------------------------------------------------------------
__global__ __launch_bounds__(256) void k_layer3(
    const float* __restrict__ H2, const float* __restrict__ W3d,
    const float* __restrict__ b3d, float* __restrict__ kout, int combine,
    float* __restrict__ y, const float* __restrict__ k1,
    const float* __restrict__ k2, const float* __restrict__ k3,
    const float* __restrict__ k4, const float* __restrict__ k5, float hb1,
    float hb2, float hb3, float hb4, float hb5, float hb6) {
  __shared__ float H2s[64][68];
  __shared__ float W3Ts[32][68];
  const int row0 = blockIdx.x * 64;
  const int c16 = threadIdx.x & 15;
  const int rgrp = threadIdx.x >> 4;

  float acc[4][2] = {};

  for (int kc = 0; kc < HID; kc += 64) {
    __syncthreads();
    {
      int r = threadIdx.x >> 2;
      int ks = (threadIdx.x & 3) * 16;
      const float* src = &H2[(size_t)(row0 + r) * HID + kc + ks];
      float4 v0 = ((const float4*)src)[0];
      float4 v1 = ((const float4*)src)[1];
      float4 v2 = ((const float4*)src)[2];
      float4 v3 = ((const float4*)src)[3];
      *(float4*)&H2s[r][ks + 0] = v0;
      *(float4*)&H2s[r][ks + 4] = v1;
      *(float4*)&H2s[r][ks + 8] = v2;
      *(float4*)&H2s[r][ks + 12] = v3;
    }
    for (int i = threadIdx.x; i < 32 * 64; i += 256) {
      int cc = i & 31, kk = i >> 5;
      W3Ts[cc][kk] = (cc < LOOK) ? W3d[(size_t)(kc + kk) * LOOK + cc] : 0.f;
    }
    __syncthreads();
#pragma unroll
    for (int k4i = 0; k4i < 16; ++k4i) {
      float4 w0 = *(const float4*)&W3Ts[c16][k4i * 4];
      float4 w1 = *(const float4*)&W3Ts[c16 + 16][k4i * 4];
#pragma unroll
      for (int i = 0; i < 4; ++i) {
        float4 hv = *(const float4*)&H2s[rgrp * 4 + i][k4i * 4];
        acc[i][0] += hv.x * w0.x + hv.y * w0.y + hv.z * w0.z + hv.w * w0.w;
        acc[i][1] += hv.x * w1.x + hv.y * w1.y + hv.z * w1.z + hv.w * w1.w;
      }
    }
  }

#pragma unroll
  for (int i = 0; i < 4; ++i) {
    const int r = row0 + rgrp * 4 + i;
#pragma unroll
    for (int jj = 0; jj < 2; ++jj) {
      const int c = c16 + jj * 16;
      if (c < LOOK) {
        const size_t idx = (size_t)r * LOOK + c;
        const float kv = acc[i][jj] + b3d[c];
        if (combine) {
          y[idx] = y[idx] + hb1 * k1[idx] + hb2 * k2[idx] + hb3 * k3[idx] +
                   hb4 * k4[idx] + hb5 * k5[idx] + hb6 * kv;
        } else {
          kout[idx] = kv;
        }
      }
    }
  }
}

// ---------------------------------------------------------------------------
__global__ __launch_bounds__(256) void k_readout(const float* __restrict__ y,
                                                 const float* __restrict__ Wf,
                                                 const float* __restrict__ bf,
                                                 float* __restrict__ out) {
  const int r = blockIdx.x * blockDim.x + threadIdx.x;
  if (r >= BATCH) return;
  float acc = bf[0];
#pragma unroll
  for (int c = 0; c < LOOK; ++c) acc += y[(size_t)r * LOOK + c] * Wf[c];
  out[r] = acc;
}

// ---------------------------------------------------------------------------
extern "C" void kernel_launch(void* const* d_in, const int* in_sizes, int n_in,
                              void* d_out, int out_size, void* d_ws,
                              size_t ws_size, hipStream_t stream) {
  const float* y0 = (const float*)d_in[0];
  const float* W1 = (const float*)d_in[1];
  const float* b1 = (const float*)d_in[2];
  const float* W2 = (const float*)d_in[3];
  const float* b2 = (const float*)d_in[4];
  const float* W3 = (const float*)d_in[5];
  const float* b3 = (const float*)d_in[6];
  const float* Wf = (const float*)d_in[7];
  const float* bf = (const float*)d_in[8];
  float* out = (float*)d_out;

  const size_t NY = (size_t)BATCH * LOOK;
  float* f = (float*)d_ws;
  float* y = f;
  float* kk[5];
  for (int i = 0; i < 5; ++i) kk[i] = f + NY * (1 + i);
  char* p = (char*)(f + NY * 6);
  short* H1h = (short*)p;
  p += (size_t)BATCH * HID * 2;
  short* H1l = (short*)p;
  p += (size_t)BATCH * HID * 2;
  float* H2 = (float*)p;
  p += (size_t)BATCH * HID * 4;
  short* W2Th = (short*)p;
  p += (size_t)HID * HID * 2;
  short* W2Tl = (short*)p;

  hipMemcpyAsync(y, y0, NY * sizeof(float), hipMemcpyDeviceToDevice, stream);

  const double hh = 1.0 / 16.0;
  static const double A[6][5] = {
      {0, 0, 0, 0, 0},
      {1.0 / 5, 0, 0, 0, 0},
      {3.0 / 40, 9.0 / 40, 0, 0, 0},
      {44.0 / 45, -56.0 / 15, 32.0 / 9, 0, 0},
      {19372.0 / 6561, -25360.0 / 2187, 64448.0 / 6561, -212.0 / 729, 0},
      {9017.0 / 3168, -355.0 / 33, 46732.0 / 5247, 49.0 / 176,
       -5103.0 / 18656},
  };
  static const double Bb[6] = {35.0 / 384,  0,              500.0 / 1113,
                               125.0 / 192, -2187.0 / 6784, 11.0 / 84};

  const float hb1 = (float)(hh * Bb[0]);
  const float hb2 = (float)(hh * Bb[1]);
  const float hb3 = (float)(hh * Bb[2]);
  const float hb4 = (float)(hh * Bb[3]);
  const float hb5 = (float)(hh * Bb[4]);
  const float hb6 = (float)(hh * Bb[5]);

  for (int d = 0; d < DEPTH; ++d) {
    const float* W1d = W1 + (size_t)d * LOOK * HID;
    const float* b1d = b1 + (size_t)d * HID;
    const float* W2d = W2 + (size_t)d * HID * HID;
    const float* b2d = b2 + (size_t)d * HID;
    const float* W3d = W3 + (size_t)d * HID * LOOK;
    const float* b3d = b3 + (size_t)d * LOOK;

    k_w2split<<<dim3(16, 16), 256, 0, stream>>>(W2d, W2Th, W2Tl);

    for (int s = 0; s < NSTEPS; ++s) {
      for (int st = 0; st < 6; ++st) {
        const float c1 = (float)(hh * A[st][0]);
        const float c2 = (float)(hh * A[st][1]);
        const float c3 = (float)(hh * A[st][2]);
        const float c4 = (float)(hh * A[st][3]);
        const float c5 = (float)(hh * A[st][4]);
        k_layer1<<<dim3(HID / 256, BATCH / 64), 256, 0, stream>>>(
            y, kk[0], kk[1], kk[2], kk[3], kk[4], c1, c2, c3, c4, c5, W1d, b1d,
            H1h, H1l);
        k_mid<<<dim3(BATCH / 128, HID / 128), 256, 0, stream>>>(
            H1h, H1l, W2Th, W2Tl, b2d, H2);
        const int comb = (st == 5) ? 1 : 0;
        float* kout = (st < 5) ? kk[st] : kk[0];
        k_layer3<<<dim3(BATCH / 64), 256, 0, stream>>>(
            H2, W3d, b3d, kout, comb, y, kk[0], kk[1], kk[2], kk[3], kk[4],
            hb1, hb2, hb3, hb4, hb5, hb6);
      }
    }
  }

  k_readout<<<dim3(BATCH / 256), 256, 0, stream>>>(y, Wf, bf, out);
}

// Round 3
// 182826.538 us; speedup vs baseline: 2.5885x; 1.0642x over previous
//
#include <hip/hip_runtime.h>

#define BATCH 16384
#define LOOK 30
#define HID 1024
#define DEPTH 10
#define NSTEPS 16
#define ALPHA 0.3f

typedef short bf16x8 __attribute__((ext_vector_type(8)));
typedef float f32x4 __attribute__((ext_vector_type(4)));

__device__ __forceinline__ float leaky(float x) { return x > 0.f ? x : ALPHA * x; }

__device__ __forceinline__ unsigned short f2bf(float x) {
  unsigned u = __builtin_bit_cast(unsigned, x);
  unsigned r = u + 0x7FFFu + ((u >> 16) & 1u);
  return (unsigned short)(r >> 16);
}
__device__ __forceinline__ float bf2f(unsigned short b) {
  return __builtin_bit_cast(float, (unsigned)b << 16);
}

#define GLD_LDS16(g, l)                                        \
  __builtin_amdgcn_global_load_lds(                            \
      (const __attribute__((address_space(1))) void*)(g),      \
      (__attribute__((address_space(3))) void*)(l), 16, 0, 0)

// ---------------------------------------------------------------------------
// Once per depth: W2[k][n] fp32 -> W2T[n][k] split into hi/lo bf16.
// ---------------------------------------------------------------------------
__global__ __launch_bounds__(256) void k_w2split(const float* __restrict__ W2d,
                                                 short* __restrict__ W2Th,
                                                 short* __restrict__ W2Tl) {
  __shared__ float t[64][65];
  const int kb = blockIdx.x * 64;
  const int nb = blockIdx.y * 64;
  for (int i = threadIdx.x; i < 4096; i += 256) {
    int r = i >> 6, c = i & 63;  // r = k, c = n
    t[r][c] = W2d[(size_t)(kb + r) * HID + nb + c];
  }
  __syncthreads();
  for (int i = threadIdx.x; i < 4096; i += 256) {
    int r = i >> 6, c = i & 63;  // r = n, c = k
    float v = t[c][r];
    unsigned short hi = f2bf(v);
    unsigned short lo = f2bf(v - bf2f(hi));
    W2Th[(size_t)(nb + r) * HID + kb + c] = (short)hi;
    W2Tl[(size_t)(nb + r) * HID + kb + c] = (short)lo;
  }
}

// ---------------------------------------------------------------------------
// Kernel A: z = y + sum_j c_j k_j ; H1 = leaky(z @ W1 + b1) as hi/lo bf16.
// grid (HID/512, BATCH/128), block 256; thread handles 2 adjacent cols.
// ---------------------------------------------------------------------------
__global__ __launch_bounds__(256) void k_layer1(
    const float* __restrict__ y, const float* __restrict__ k1,
    const float* __restrict__ k2, const float* __restrict__ k3,
    const float* __restrict__ k4, const float* __restrict__ k5, float c1,
    float c2, float c3, float c4, float c5, const float* __restrict__ W1d,
    const float* __restrict__ b1d, short* __restrict__ H1h,
    short* __restrict__ H1l) {
  __shared__ float zs[128][32];
  const int row0 = blockIdx.y * 128;
  const int c0 = blockIdx.x * 512 + threadIdx.x * 2;

  for (int i = threadIdx.x; i < 128 * 32; i += 256) {
    int r = i >> 5, c = i & 31;
    float v = 0.f;
    if (c < LOOK) {
      size_t idx = (size_t)(row0 + r) * LOOK + c;
      v = y[idx] + c1 * k1[idx] + c2 * k2[idx] + c3 * k3[idx] + c4 * k4[idx] +
          c5 * k5[idx];
    }
    zs[r][c] = v;
  }
  __syncthreads();

  float wa[32], wb[32];
#pragma unroll
  for (int k = 0; k < LOOK; ++k) {
    float2 w2 = *(const float2*)&W1d[(size_t)k * HID + c0];
    wa[k] = w2.x;
    wb[k] = w2.y;
  }
  wa[30] = wa[31] = wb[30] = wb[31] = 0.f;
  const float2 b2v = *(const float2*)&b1d[c0];

  for (int r = 0; r < 128; ++r) {
    float a0 = b2v.x, a1 = b2v.y;
#pragma unroll
    for (int k4i = 0; k4i < 8; ++k4i) {
      float4 zv = *(const float4*)&zs[r][k4i * 4];
      a0 += zv.x * wa[k4i * 4 + 0] + zv.y * wa[k4i * 4 + 1] +
            zv.z * wa[k4i * 4 + 2] + zv.w * wa[k4i * 4 + 3];
      a1 += zv.x * wb[k4i * 4 + 0] + zv.y * wb[k4i * 4 + 1] +
            zv.z * wb[k4i * 4 + 2] + zv.w * wb[k4i * 4 + 3];
    }
    float h0 = leaky(a0), h1 = leaky(a1);
    unsigned short h0h = f2bf(h0), h1h = f2bf(h1);
    unsigned short h0l = f2bf(h0 - bf2f(h0h)), h1l = f2bf(h1 - bf2f(h1h));
    const size_t o = (size_t)(row0 + r) * HID + c0;
    short2 sh, sl;
    sh.x = (short)h0h; sh.y = (short)h1h;
    sl.x = (short)h0l; sl.y = (short)h1l;
    *(short2*)&H1h[o] = sh;
    *(short2*)&H1l[o] = sl;
  }
}

// ---------------------------------------------------------------------------
// Kernel B (MFMA): H2 = leaky(H1 @ W2 + b2), split-bf16 3-product.
// 256x256 tile, BK=32, 8 waves (2M x 4N), double-buffered 128KB LDS,
// prefetch-before-compute (T3 minimum), XOR-swizzled rows (T2, both sides).
// LDS row = 128B = [hi 64B | lo 64B], slot(16B) phys = logical ^ (row&7).
// grid: 256 blocks (64 M x 4 N), XCD-chunked swizzle.
// ---------------------------------------------------------------------------
__global__ __launch_bounds__(512, 2) void k_mid(
    const short* __restrict__ H1h, const short* __restrict__ H1l,
    const short* __restrict__ W2Th, const short* __restrict__ W2Tl,
    const float* __restrict__ b2d, float* __restrict__ H2) {
  __shared__ char lds[131072];  // 2 buffers x (A 32KB | B 32KB)

  const int tid = threadIdx.x;
  const int lane = tid & 63;
  const int wave = tid >> 6;

  // bijective XCD swizzle: 256 blocks, 8 XCDs, 32 per chunk
  const int bid = blockIdx.x;
  const int wg = (bid & 7) * 32 + (bid >> 3);
  const int mb = wg >> 2, nb = wg & 3;
  const int row0 = mb * 256;
  const int n0 = nb * 256;
  const int wm = wave >> 2;         // 0..1 (M half)
  const int wnb = wave & 3;         // 0..3 (N quarter)

  // ---- staging setup: wave w loads chunks w*8..w*8+7 (1KB = 8 rows x 128B)
  const int l3 = lane >> 3;   // row within chunk (0..7)
  const int l7 = lane & 7;    // dest slot
  const int s = l7 ^ l3;      // logical slot to fetch (swizzle pre-applied)
  const char* hsrc;
  const char* lsrc;
  int rbase;
  if (wave < 4) {
    hsrc = (const char*)H1h;
    lsrc = (const char*)H1l;
    rbase = row0;
  } else {
    hsrc = (const char*)W2Th;
    lsrc = (const char*)W2Tl;
    rbase = n0;
  }
  const char* srcB[8];
#pragma unroll
  for (int i = 0; i < 8; ++i) {
    const int c = wave * 8 + i;
    const int rloc = (c & 31) * 8 + l3;
    const char* base = (s < 4) ? hsrc : lsrc;
    srcB[i] = base + (size_t)(rbase + rloc) * 2048 + (size_t)(s & 3) * 16;
  }
  const int dchunk0 = wave * 8 * 1024;

  // ---- ds_read offsets (per piece p: 0=hi, 1=lo)
  // A row_local = wm*128 + mi*16 + (lane&15); B row_local = wnb*64 + nj*16 + (lane&15)
  // phys slot = (p*4 + (lane>>4)) ^ (row&7), row&7 = lane&7
  int offA0, offA1, offB0, offB1;
  {
    const int r15 = lane & 15;
    const int kq = lane >> 4;
    const int pa0 = ((0 * 4 + kq) ^ l7) * 16;
    const int pa1 = ((1 * 4 + kq) ^ l7) * 16;
    offA0 = (wm * 128 + r15) * 128 + pa0;
    offA1 = (wm * 128 + r15) * 128 + pa1;
    offB0 = 32768 + (wnb * 64 + r15) * 128 + pa0;
    offB1 = 32768 + (wnb * 64 + r15) * 128 + pa1;
  }

  f32x4 acc[8][4];
#pragma unroll
  for (int i = 0; i < 8; ++i)
#pragma unroll
    for (int j = 0; j < 4; ++j) acc[i][j] = (f32x4){0.f, 0.f, 0.f, 0.f};

#define STAGE(buf, kb)                                                   \
  {                                                                      \
    _Pragma("unroll") for (int i = 0; i < 8; ++i) {                      \
      GLD_LDS16(srcB[i] + (kb), &lds[(buf)*65536 + dchunk0 + i * 1024]); \
    }                                                                    \
  }

  STAGE(0, 0);
  __syncthreads();  // drain vmcnt + barrier: buf0 ready

  int cur = 0;
  for (int t = 0; t < 32; ++t) {
    if (t < 31) STAGE(cur ^ 1, (t + 1) * 64);  // prefetch next K-tile

    const char* buf = &lds[cur * 65536];
    bf16x8 bh[4], bl[4];
#pragma unroll
    for (int nj = 0; nj < 4; ++nj) {
      bh[nj] = *(const bf16x8*)(buf + offB0 + nj * 2048);
      bl[nj] = *(const bf16x8*)(buf + offB1 + nj * 2048);
    }
#pragma unroll
    for (int mi = 0; mi < 8; ++mi) {
      bf16x8 ah = *(const bf16x8*)(buf + offA0 + mi * 2048);
      bf16x8 al = *(const bf16x8*)(buf + offA1 + mi * 2048);
#pragma unroll
      for (int nj = 0; nj < 4; ++nj) {
        acc[mi][nj] =
            __builtin_amdgcn_mfma_f32_16x16x32_bf16(ah, bh[nj], acc[mi][nj], 0, 0, 0);
        acc[mi][nj] =
            __builtin_amdgcn_mfma_f32_16x16x32_bf16(ah, bl[nj], acc[mi][nj], 0, 0, 0);
        acc[mi][nj] =
            __builtin_amdgcn_mfma_f32_16x16x32_bf16(al, bh[nj], acc[mi][nj], 0, 0, 0);
      }
    }
    __syncthreads();  // drains this tile's prefetch vmcnt + syncs buffer swap
    cur ^= 1;
  }
#undef STAGE

  // epilogue: C/D layout col = lane&15 (N), row = (lane>>4)*4 + reg (M)
  const int crow = (lane >> 4) * 4;
  const int ccol = lane & 15;
#pragma unroll
  for (int nj = 0; nj < 4; ++nj) {
    const int col = n0 + wnb * 64 + nj * 16 + ccol;
    const float bv = b2d[col];
#pragma unroll
    for (int mi = 0; mi < 8; ++mi) {
      const int rb = row0 + wm * 128 + mi * 16 + crow;
#pragma unroll
      for (int r = 0; r < 4; ++r) {
        H2[(size_t)(rb + r) * HID + col] = leaky(acc[mi][nj][r] + bv);
      }
    }
  }
}

// ---------------------------------------------------------------------------
// Kernel C: k_out = H2 @ W3 + b3 ; if combine: y += sum hb_j k_j.
// 32 rows/block -> grid BATCH/32 = 512 blocks, 256 threads.
// ---------------------------------------------------------------------------
__global__ __launch_bounds__(256) void k_layer3(
    const float* __restrict__ H2, const float* __restrict__ W3d,
    const float* __restrict__ b3d, float* __restrict__ kout, int combine,
    float* __restrict__ y, const float* __restrict__ k1,
    const float* __restrict__ k2, const float* __restrict__ k3,
    const float* __restrict__ k4, const float* __restrict__ k5, float hb1,
    float hb2, float hb3, float hb4, float hb5, float hb6) {
  __shared__ float H2s[32][68];
  __shared__ float W3Ts[32][68];
  const int row0 = blockIdx.x * 32;
  const int c16 = threadIdx.x & 15;
  const int rgrp = threadIdx.x >> 4;  // 0..15

  float acc[2][2] = {};

  for (int kc = 0; kc < HID; kc += 64) {
    __syncthreads();
    {
      int r = threadIdx.x >> 3;        // 0..31
      int ks = (threadIdx.x & 7) * 8;  // 0..56
      const float* src = &H2[(size_t)(row0 + r) * HID + kc + ks];
      float4 v0 = ((const float4*)src)[0];
      float4 v1 = ((const float4*)src)[1];
      *(float4*)&H2s[r][ks + 0] = v0;
      *(float4*)&H2s[r][ks + 4] = v1;
    }
    for (int i = threadIdx.x; i < 32 * 64; i += 256) {
      int cc = i & 31, kk = i >> 5;
      W3Ts[cc][kk] = (cc < LOOK) ? W3d[(size_t)(kc + kk) * LOOK + cc] : 0.f;
    }
    __syncthreads();
#pragma unroll
    for (int k4i = 0; k4i < 16; ++k4i) {
      float4 w0 = *(const float4*)&W3Ts[c16][k4i * 4];
      float4 w1 = *(const float4*)&W3Ts[c16 + 16][k4i * 4];
#pragma unroll
      for (int i = 0; i < 2; ++i) {
        float4 hv = *(const float4*)&H2s[rgrp * 2 + i][k4i * 4];
        acc[i][0] += hv.x * w0.x + hv.y * w0.y + hv.z * w0.z + hv.w * w0.w;
        acc[i][1] += hv.x * w1.x + hv.y * w1.y + hv.z * w1.z + hv.w * w1.w;
      }
    }
  }

#pragma unroll
  for (int i = 0; i < 2; ++i) {
    const int r = row0 + rgrp * 2 + i;
#pragma unroll
    for (int jj = 0; jj < 2; ++jj) {
      const int c = c16 + jj * 16;
      if (c < LOOK) {
        const size_t idx = (size_t)r * LOOK + c;
        const float kv = acc[i][jj] + b3d[c];
        if (combine) {
          y[idx] = y[idx] + hb1 * k1[idx] + hb2 * k2[idx] + hb3 * k3[idx] +
                   hb4 * k4[idx] + hb5 * k5[idx] + hb6 * kv;
        } else {
          kout[idx] = kv;
        }
      }
    }
  }
}

// ---------------------------------------------------------------------------
__global__ __launch_bounds__(256) void k_readout(const float* __restrict__ y,
                                                 const float* __restrict__ Wf,
                                                 const float* __restrict__ bf,
                                                 float* __restrict__ out) {
  const int r = blockIdx.x * blockDim.x + threadIdx.x;
  if (r >= BATCH) return;
  float acc = bf[0];
#pragma unroll
  for (int c = 0; c < LOOK; ++c) acc += y[(size_t)r * LOOK + c] * Wf[c];
  out[r] = acc;
}

// ---------------------------------------------------------------------------
extern "C" void kernel_launch(void* const* d_in, const int* in_sizes, int n_in,
                              void* d_out, int out_size, void* d_ws,
                              size_t ws_size, hipStream_t stream) {
  const float* y0 = (const float*)d_in[0];
  const float* W1 = (const float*)d_in[1];
  const float* b1 = (const float*)d_in[2];
  const float* W2 = (const float*)d_in[3];
  const float* b2 = (const float*)d_in[4];
  const float* W3 = (const float*)d_in[5];
  const float* b3 = (const float*)d_in[6];
  const float* Wf = (const float*)d_in[7];
  const float* bf = (const float*)d_in[8];
  float* out = (float*)d_out;

  const size_t NY = (size_t)BATCH * LOOK;
  float* f = (float*)d_ws;
  float* y = f;
  float* kk[5];
  for (int i = 0; i < 5; ++i) kk[i] = f + NY * (1 + i);
  char* p = (char*)(f + NY * 6);
  short* H1h = (short*)p;
  p += (size_t)BATCH * HID * 2;
  short* H1l = (short*)p;
  p += (size_t)BATCH * HID * 2;
  float* H2 = (float*)p;
  p += (size_t)BATCH * HID * 4;
  short* W2Th = (short*)p;
  p += (size_t)HID * HID * 2;
  short* W2Tl = (short*)p;

  hipMemcpyAsync(y, y0, NY * sizeof(float), hipMemcpyDeviceToDevice, stream);

  const double hh = 1.0 / 16.0;
  static const double A[6][5] = {
      {0, 0, 0, 0, 0},
      {1.0 / 5, 0, 0, 0, 0},
      {3.0 / 40, 9.0 / 40, 0, 0, 0},
      {44.0 / 45, -56.0 / 15, 32.0 / 9, 0, 0},
      {19372.0 / 6561, -25360.0 / 2187, 64448.0 / 6561, -212.0 / 729, 0},
      {9017.0 / 3168, -355.0 / 33, 46732.0 / 5247, 49.0 / 176,
       -5103.0 / 18656},
  };
  static const double Bb[6] = {35.0 / 384,  0,              500.0 / 1113,
                               125.0 / 192, -2187.0 / 6784, 11.0 / 84};

  const float hb1 = (float)(hh * Bb[0]);
  const float hb2 = (float)(hh * Bb[1]);
  const float hb3 = (float)(hh * Bb[2]);
  const float hb4 = (float)(hh * Bb[3]);
  const float hb5 = (float)(hh * Bb[4]);
  const float hb6 = (float)(hh * Bb[5]);

  for (int d = 0; d < DEPTH; ++d) {
    const float* W1d = W1 + (size_t)d * LOOK * HID;
    const float* b1d = b1 + (size_t)d * HID;
    const float* W2d = W2 + (size_t)d * HID * HID;
    const float* b2d = b2 + (size_t)d * HID;
    const float* W3d = W3 + (size_t)d * HID * LOOK;
    const float* b3d = b3 + (size_t)d * LOOK;

    k_w2split<<<dim3(16, 16), 256, 0, stream>>>(W2d, W2Th, W2Tl);

    for (int s = 0; s < NSTEPS; ++s) {
      for (int st = 0; st < 6; ++st) {
        const float c1 = (float)(hh * A[st][0]);
        const float c2 = (float)(hh * A[st][1]);
        const float c3 = (float)(hh * A[st][2]);
        const float c4 = (float)(hh * A[st][3]);
        const float c5 = (float)(hh * A[st][4]);
        k_layer1<<<dim3(HID / 512, BATCH / 128), 256, 0, stream>>>(
            y, kk[0], kk[1], kk[2], kk[3], kk[4], c1, c2, c3, c4, c5, W1d, b1d,
            H1h, H1l);
        k_mid<<<dim3(256), 512, 0, stream>>>(H1h, H1l, W2Th, W2Tl, b2d, H2);
        const int comb = (st == 5) ? 1 : 0;
        float* kout = (st < 5) ? kk[st] : kk[0];
        k_layer3<<<dim3(BATCH / 32), 256, 0, stream>>>(
            H2, W3d, b3d, kout, comb, y, kk[0], kk[1], kk[2], kk[3], kk[4],
            hb1, hb2, hb3, hb4, hb5, hb6);
      }
    }
  }

  k_readout<<<dim3(BATCH / 256), 256, 0, stream>>>(y, Wf, bf, out);
}

// Round 4
// 137603.406 us; speedup vs baseline: 3.4392x; 1.3286x over previous
//
#include <hip/hip_runtime.h>

#define BATCH 16384
#define LOOK 30
#define HID 1024
#define DEPTH 10
#define NSTEPS 16
#define ALPHA 0.3f

typedef short bf16x8 __attribute__((ext_vector_type(8)));
typedef float f32x4 __attribute__((ext_vector_type(4)));

__device__ __forceinline__ float leaky(float x) { return x > 0.f ? x : ALPHA * x; }

__device__ __forceinline__ unsigned short f2bf(float x) {
  unsigned u = __builtin_bit_cast(unsigned, x);
  unsigned r = u + 0x7FFFu + ((u >> 16) & 1u);
  return (unsigned short)(r >> 16);
}
__device__ __forceinline__ float bf2f(unsigned short b) {
  return __builtin_bit_cast(float, (unsigned)b << 16);
}

#define GLD_LDS16(g, l)                                        \
  __builtin_amdgcn_global_load_lds(                            \
      (const __attribute__((address_space(1))) void*)(g),      \
      (__attribute__((address_space(3))) void*)(l), 16, 0, 0)

// ---------------------------------------------------------------------------
// Prep: W2[k][n] -> W2T[n][k] hi/lo bf16. grid (16,16), 256 thr.
// ---------------------------------------------------------------------------
__global__ __launch_bounds__(256) void k_w2split(const float* __restrict__ W2d,
                                                 short* __restrict__ W2Th,
                                                 short* __restrict__ W2Tl) {
  __shared__ float t[64][65];
  const int kb = blockIdx.x * 64;
  const int nb = blockIdx.y * 64;
  for (int i = threadIdx.x; i < 4096; i += 256) {
    int r = i >> 6, c = i & 63;
    t[r][c] = W2d[(size_t)(kb + r) * HID + nb + c];
  }
  __syncthreads();
  for (int i = threadIdx.x; i < 4096; i += 256) {
    int r = i >> 6, c = i & 63;
    float v = t[c][r];
    unsigned short hi = f2bf(v);
    unsigned short lo = f2bf(v - bf2f(hi));
    W2Th[(size_t)(nb + r) * HID + kb + c] = (short)hi;
    W2Tl[(size_t)(nb + r) * HID + kb + c] = (short)lo;
  }
}

// Prep: W1[30][1024] -> W1T[1024 n][32 k] hi/lo (k 30,31 zero). grid 128.
__global__ __launch_bounds__(256) void k_w1t(const float* __restrict__ W1d,
                                             short* __restrict__ W1Th,
                                             short* __restrict__ W1Tl) {
  const int idx = blockIdx.x * 256 + threadIdx.x;
  if (idx >= 1024 * 32) return;
  const int n = idx >> 5, k = idx & 31;
  float v = (k < LOOK) ? W1d[(size_t)k * HID + n] : 0.f;
  unsigned short hi = f2bf(v);
  unsigned short lo = f2bf(v - bf2f(hi));
  W1Th[idx] = (short)hi;
  W1Tl[idx] = (short)lo;
}

// Prep: W3[1024][30] -> W3T[32 n][1024 k] hi/lo (n 30,31 zero). grid 128.
__global__ __launch_bounds__(256) void k_w3t(const float* __restrict__ W3d,
                                             short* __restrict__ W3Th,
                                             short* __restrict__ W3Tl) {
  const int idx = blockIdx.x * 256 + threadIdx.x;
  if (idx >= 32 * 1024) return;
  const int n = idx >> 10, k = idx & 1023;
  float v = (n < LOOK) ? W3d[(size_t)k * LOOK + n] : 0.f;
  unsigned short hi = f2bf(v);
  unsigned short lo = f2bf(v - bf2f(hi));
  W3Th[idx] = (short)hi;
  W3Tl[idx] = (short)lo;
}

// Init: z = y0 (padded to 32 cols) hi/lo. grid 2048.
__global__ __launch_bounds__(256) void k_zinit(const float* __restrict__ y0,
                                               short* __restrict__ zh,
                                               short* __restrict__ zl) {
  const int idx = blockIdx.x * 256 + threadIdx.x;
  if (idx >= BATCH * 32) return;
  const int r = idx >> 5, c = idx & 31;
  float v = (c < LOOK) ? y0[(size_t)r * LOOK + c] : 0.f;
  unsigned short hi = f2bf(v);
  unsigned short lo = f2bf(v - bf2f(hi));
  zh[idx] = (short)hi;
  zl[idx] = (short)lo;
}

// ---------------------------------------------------------------------------
// Layer1 (MFMA): H1 = leaky(z @ W1 + b1), single K-tile (K=32).
// Block 512 thr / 8 waves (2M x 4N), tile M=128 x N=256, wave 64x64.
// A (z hi/lo) staged via global_load_lds; B (W1T) direct global->reg.
// grid (BATCH/128, HID/256) = (128, 4).
// ---------------------------------------------------------------------------
__global__ __launch_bounds__(512, 2) void k_l1(
    const short* __restrict__ zh, const short* __restrict__ zl,
    const short* __restrict__ W1Th, const short* __restrict__ W1Tl,
    const float* __restrict__ b1d, short* __restrict__ H1h,
    short* __restrict__ H1l) {
  __shared__ short za[2][128 * 32];
  const int tid = threadIdx.x, lane = tid & 63, wave = tid >> 6;
  const int row0 = blockIdx.x * 128;
  const int n0 = blockIdx.y * 256;
  const int wm = wave >> 2, wn = wave & 3;
  const int r15 = lane & 15;
  const int bk = (lane >> 4) * 8;

  // B fragments direct from global (coalesced 1KB per read, L2-hot)
  bf16x8 bh[4], bl[4];
#pragma unroll
  for (int nj = 0; nj < 4; ++nj) {
    const size_t bo = (size_t)(n0 + wn * 64 + nj * 16 + r15) * 32 + bk;
    bh[nj] = *(const bf16x8*)&W1Th[bo];
    bl[nj] = *(const bf16x8*)&W1Tl[bo];
  }

  // stage z tile (A), linear
  GLD_LDS16((const char*)(zh + (size_t)row0 * 32) + tid * 16, &za[0][tid * 8]);
  GLD_LDS16((const char*)(zl + (size_t)row0 * 32) + tid * 16, &za[1][tid * 8]);
  __syncthreads();

  bf16x8 ah[4], al[4];
#pragma unroll
  for (int mi = 0; mi < 4; ++mi) {
    const int ao = (wm * 64 + mi * 16 + r15) * 32 + bk;
    ah[mi] = *(const bf16x8*)&za[0][ao];
    al[mi] = *(const bf16x8*)&za[1][ao];
  }

  f32x4 acc[4][4];
#pragma unroll
  for (int i = 0; i < 4; ++i)
#pragma unroll
    for (int j = 0; j < 4; ++j) acc[i][j] = (f32x4){0.f, 0.f, 0.f, 0.f};

#pragma unroll
  for (int mi = 0; mi < 4; ++mi)
#pragma unroll
    for (int nj = 0; nj < 4; ++nj) {
      acc[mi][nj] = __builtin_amdgcn_mfma_f32_16x16x32_bf16(ah[mi], bh[nj],
                                                            acc[mi][nj], 0, 0, 0);
      acc[mi][nj] = __builtin_amdgcn_mfma_f32_16x16x32_bf16(ah[mi], bl[nj],
                                                            acc[mi][nj], 0, 0, 0);
      acc[mi][nj] = __builtin_amdgcn_mfma_f32_16x16x32_bf16(al[mi], bh[nj],
                                                            acc[mi][nj], 0, 0, 0);
    }

  const int crow = (lane >> 4) * 4;
#pragma unroll
  for (int nj = 0; nj < 4; ++nj) {
    const int col = n0 + wn * 64 + nj * 16 + r15;
    const float bias = b1d[col];
#pragma unroll
    for (int mi = 0; mi < 4; ++mi) {
      const int rb = row0 + wm * 64 + mi * 16 + crow;
#pragma unroll
      for (int r = 0; r < 4; ++r) {
        float v = leaky(acc[mi][nj][r] + bias);
        unsigned short hi = f2bf(v);
        unsigned short lo = f2bf(v - bf2f(hi));
        const size_t o = (size_t)(rb + r) * HID + col;
        H1h[o] = (short)hi;
        H1l[o] = (short)lo;
      }
    }
  }
}

// ---------------------------------------------------------------------------
// Mid (MFMA): H2 = leaky(H1 @ W2 + b2) hi/lo out. (structure as round 3)
// ---------------------------------------------------------------------------
__global__ __launch_bounds__(512, 2) void k_mid(
    const short* __restrict__ H1h, const short* __restrict__ H1l,
    const short* __restrict__ W2Th, const short* __restrict__ W2Tl,
    const float* __restrict__ b2d, short* __restrict__ H2h,
    short* __restrict__ H2l) {
  __shared__ char lds[131072];

  const int tid = threadIdx.x;
  const int lane = tid & 63;
  const int wave = tid >> 6;

  const int bid = blockIdx.x;
  const int wg = (bid & 7) * 32 + (bid >> 3);
  const int mb = wg >> 2, nb = wg & 3;
  const int row0 = mb * 256;
  const int n0 = nb * 256;
  const int wm = wave >> 2;
  const int wnb = wave & 3;

  const int l3 = lane >> 3;
  const int l7 = lane & 7;
  const int s = l7 ^ l3;
  const char* hsrc;
  const char* lsrc;
  int rbase;
  if (wave < 4) {
    hsrc = (const char*)H1h;
    lsrc = (const char*)H1l;
    rbase = row0;
  } else {
    hsrc = (const char*)W2Th;
    lsrc = (const char*)W2Tl;
    rbase = n0;
  }
  const char* srcB[8];
#pragma unroll
  for (int i = 0; i < 8; ++i) {
    const int c = wave * 8 + i;
    const int rloc = (c & 31) * 8 + l3;
    const char* base = (s < 4) ? hsrc : lsrc;
    srcB[i] = base + (size_t)(rbase + rloc) * 2048 + (size_t)(s & 3) * 16;
  }
  const int dchunk0 = wave * 8 * 1024;

  int offA0, offA1, offB0, offB1;
  {
    const int r15 = lane & 15;
    const int kq = lane >> 4;
    const int pa0 = ((0 * 4 + kq) ^ l7) * 16;
    const int pa1 = ((1 * 4 + kq) ^ l7) * 16;
    offA0 = (wm * 128 + r15) * 128 + pa0;
    offA1 = (wm * 128 + r15) * 128 + pa1;
    offB0 = 32768 + (wnb * 64 + r15) * 128 + pa0;
    offB1 = 32768 + (wnb * 64 + r15) * 128 + pa1;
  }

  f32x4 acc[8][4];
#pragma unroll
  for (int i = 0; i < 8; ++i)
#pragma unroll
    for (int j = 0; j < 4; ++j) acc[i][j] = (f32x4){0.f, 0.f, 0.f, 0.f};

#define STAGE(buf, kb)                                                   \
  {                                                                      \
    _Pragma("unroll") for (int i = 0; i < 8; ++i) {                      \
      GLD_LDS16(srcB[i] + (kb), &lds[(buf)*65536 + dchunk0 + i * 1024]); \
    }                                                                    \
  }

  STAGE(0, 0);
  __syncthreads();

  int cur = 0;
  for (int t = 0; t < 32; ++t) {
    if (t < 31) STAGE(cur ^ 1, (t + 1) * 64);

    const char* buf = &lds[cur * 65536];
    bf16x8 bh[4], bl[4];
#pragma unroll
    for (int nj = 0; nj < 4; ++nj) {
      bh[nj] = *(const bf16x8*)(buf + offB0 + nj * 2048);
      bl[nj] = *(const bf16x8*)(buf + offB1 + nj * 2048);
    }
#pragma unroll
    for (int mi = 0; mi < 8; ++mi) {
      bf16x8 ah = *(const bf16x8*)(buf + offA0 + mi * 2048);
      bf16x8 al = *(const bf16x8*)(buf + offA1 + mi * 2048);
#pragma unroll
      for (int nj = 0; nj < 4; ++nj) {
        acc[mi][nj] =
            __builtin_amdgcn_mfma_f32_16x16x32_bf16(ah, bh[nj], acc[mi][nj], 0, 0, 0);
        acc[mi][nj] =
            __builtin_amdgcn_mfma_f32_16x16x32_bf16(ah, bl[nj], acc[mi][nj], 0, 0, 0);
        acc[mi][nj] =
            __builtin_amdgcn_mfma_f32_16x16x32_bf16(al, bh[nj], acc[mi][nj], 0, 0, 0);
      }
    }
    __syncthreads();
    cur ^= 1;
  }
#undef STAGE

  const int crow = (lane >> 4) * 4;
  const int ccol = lane & 15;
#pragma unroll
  for (int nj = 0; nj < 4; ++nj) {
    const int col = n0 + wnb * 64 + nj * 16 + ccol;
    const float bv = b2d[col];
#pragma unroll
    for (int mi = 0; mi < 8; ++mi) {
      const int rb = row0 + wm * 128 + mi * 16 + crow;
#pragma unroll
      for (int r = 0; r < 4; ++r) {
        float v = leaky(acc[mi][nj][r] + bv);
        unsigned short hi = f2bf(v);
        unsigned short lo = f2bf(v - bf2f(hi));
        const size_t o = (size_t)(rb + r) * HID + col;
        H2h[o] = (short)hi;
        H2l[o] = (short)lo;
      }
    }
  }
}

// ---------------------------------------------------------------------------
// Layer3 (MFMA): kout = H2 @ W3 + b3; fused DoPri combine and/or next-z.
// Block 256 thr / 4 waves (2M x 2N), tile M=32 x N=32, K=1024 in 32 tiles.
// Double-buffered, prefetch-first, XOR-swizzled (both sides).
// grid BATCH/32 = 512.
// ---------------------------------------------------------------------------
__global__ __launch_bounds__(256, 4) void k_l3(
    const short* __restrict__ H2h, const short* __restrict__ H2l,
    const short* __restrict__ W3Th, const short* __restrict__ W3Tl,
    const float* __restrict__ b3d, float* __restrict__ kout,
    const float* __restrict__ K0, const float* __restrict__ K1,
    const float* __restrict__ K2, const float* __restrict__ K3,
    const float* __restrict__ K4, float* __restrict__ y,
    short* __restrict__ zh, short* __restrict__ zl, int combine, float p1,
    float p2, float p3, float p4, float p5, float pc, float hb1, float hb2,
    float hb3, float hb4, float hb5, float hb6) {
  __shared__ short lds[2][4096];  // per buf: A hi(1024) lo(1024) | B hi lo

  const int tid = threadIdx.x, lane = tid & 63, wave = tid >> 6;
  const int row0 = blockIdx.x * 32;
  const int wm = wave & 1, wn = wave >> 1;

  // staging map: tid<128 -> hi piece, else lo. idx in 0..127: row, slot.
  const int half = tid >> 7;
  const int idx = tid & 127;
  const int srow = idx >> 2;
  const int sd = idx & 3;
  const int slog = sd ^ ((srow >> 1) & 3);
  const short* Asrc = half ? H2l : H2h;
  const short* Bsrc = half ? W3Tl : W3Th;
  const char* aSrc = (const char*)(Asrc + (size_t)(row0 + srow) * HID) + slog * 16;
  const char* bSrc = (const char*)(Bsrc + (size_t)srow * HID) + slog * 16;
  short* aDst0 = &lds[0][half * 1024 + idx * 8];
  short* bDst0 = &lds[0][2048 + half * 1024 + idx * 8];
  short* aDst1 = &lds[1][half * 1024 + idx * 8];
  short* bDst1 = &lds[1][2048 + half * 1024 + idx * 8];

  // frag read offsets (shorts)
  const int r15 = lane & 15;
  const int kc = lane >> 4;
  const int aRow = wm * 16 + r15;
  const int bRow = wn * 16 + r15;
  const int aOff = aRow * 32 + (kc ^ ((aRow >> 1) & 3)) * 8;
  const int bOff = 2048 + bRow * 32 + (kc ^ ((bRow >> 1) & 3)) * 8;

  f32x4 acc = (f32x4){0.f, 0.f, 0.f, 0.f};

#define STAGE3(ad, bd, kb)          \
  {                                 \
    GLD_LDS16(aSrc + (kb), (ad));   \
    GLD_LDS16(bSrc + (kb), (bd));   \
  }

  STAGE3(aDst0, bDst0, 0);
  __syncthreads();

  for (int t = 0; t < 32; ++t) {
    const int cur = t & 1;
    if (t < 31) {
      if (cur == 0) STAGE3(aDst1, bDst1, (t + 1) * 64)
      else STAGE3(aDst0, bDst0, (t + 1) * 64)
    }
    const short* buf = lds[cur];
    bf16x8 ah = *(const bf16x8*)(buf + aOff);
    bf16x8 al = *(const bf16x8*)(buf + 1024 + aOff);
    bf16x8 bh = *(const bf16x8*)(buf + bOff);
    bf16x8 bl = *(const bf16x8*)(buf + 1024 + bOff);
    acc = __builtin_amdgcn_mfma_f32_16x16x32_bf16(ah, bh, acc, 0, 0, 0);
    acc = __builtin_amdgcn_mfma_f32_16x16x32_bf16(ah, bl, acc, 0, 0, 0);
    acc = __builtin_amdgcn_mfma_f32_16x16x32_bf16(al, bh, acc, 0, 0, 0);
    __syncthreads();
  }
#undef STAGE3

  // epilogue: col = wn*16 + (lane&15); rows = row0 + wm*16 + (lane>>4)*4 + r
  const int c = wn * 16 + r15;
  const int rb = row0 + wm * 16 + (lane >> 4) * 4;
  const float bias = (c < LOOK) ? b3d[c] : 0.f;
#pragma unroll
  for (int r = 0; r < 4; ++r) {
    const int row = rb + r;
    const float kv = acc[r] + bias;
    float zv = 0.f;
    if (c < LOOK) {
      const size_t id = (size_t)row * LOOK + c;
      const float yv = y[id];
      if (combine) {
        float yn = yv + hb1 * K0[id] + hb2 * K1[id] + hb3 * K2[id] +
                   hb4 * K3[id] + hb5 * K4[id] + hb6 * kv;
        y[id] = yn;
        zv = yn;
      } else {
        kout[id] = kv;
        zv = yv + pc * kv;
        if (p1 != 0.f) zv += p1 * K0[id];
        if (p2 != 0.f) zv += p2 * K1[id];
        if (p3 != 0.f) zv += p3 * K2[id];
        if (p4 != 0.f) zv += p4 * K3[id];
        if (p5 != 0.f) zv += p5 * K4[id];
      }
    }
    unsigned short hi = f2bf(zv);
    unsigned short lo = f2bf(zv - bf2f(hi));
    const size_t zo = (size_t)row * 32 + c;
    zh[zo] = (short)hi;
    zl[zo] = (short)lo;
  }
}

// ---------------------------------------------------------------------------
__global__ __launch_bounds__(256) void k_readout(const float* __restrict__ y,
                                                 const float* __restrict__ Wf,
                                                 const float* __restrict__ bf,
                                                 float* __restrict__ out) {
  const int r = blockIdx.x * blockDim.x + threadIdx.x;
  if (r >= BATCH) return;
  float acc = bf[0];
#pragma unroll
  for (int c = 0; c < LOOK; ++c) acc += y[(size_t)r * LOOK + c] * Wf[c];
  out[r] = acc;
}

// ---------------------------------------------------------------------------
extern "C" void kernel_launch(void* const* d_in, const int* in_sizes, int n_in,
                              void* d_out, int out_size, void* d_ws,
                              size_t ws_size, hipStream_t stream) {
  const float* y0 = (const float*)d_in[0];
  const float* W1 = (const float*)d_in[1];
  const float* b1 = (const float*)d_in[2];
  const float* W2 = (const float*)d_in[3];
  const float* b2 = (const float*)d_in[4];
  const float* W3 = (const float*)d_in[5];
  const float* b3 = (const float*)d_in[6];
  const float* Wf = (const float*)d_in[7];
  const float* bf = (const float*)d_in[8];
  float* out = (float*)d_out;

  const size_t NY = (size_t)BATCH * LOOK;
  float* f = (float*)d_ws;
  float* y = f;
  float* kk[5];
  for (int i = 0; i < 5; ++i) kk[i] = f + NY * (1 + i);
  char* p = (char*)(f + NY * 6);
  short* zh = (short*)p; p += (size_t)BATCH * 32 * 2;
  short* zl = (short*)p; p += (size_t)BATCH * 32 * 2;
  short* H1h = (short*)p; p += (size_t)BATCH * HID * 2;
  short* H1l = (short*)p; p += (size_t)BATCH * HID * 2;
  short* H2h = (short*)p; p += (size_t)BATCH * HID * 2;
  short* H2l = (short*)p; p += (size_t)BATCH * HID * 2;
  short* W2Th = (short*)p; p += (size_t)HID * HID * 2;
  short* W2Tl = (short*)p; p += (size_t)HID * HID * 2;
  short* W1Th = (short*)p; p += (size_t)HID * 32 * 2;
  short* W1Tl = (short*)p; p += (size_t)HID * 32 * 2;
  short* W3Th = (short*)p; p += (size_t)32 * HID * 2;
  short* W3Tl = (short*)p;

  hipMemcpyAsync(y, y0, NY * sizeof(float), hipMemcpyDeviceToDevice, stream);
  k_zinit<<<dim3(BATCH * 32 / 256), 256, 0, stream>>>(y0, zh, zl);

  const double hh = 1.0 / 16.0;
  static const double A[6][5] = {
      {0, 0, 0, 0, 0},
      {1.0 / 5, 0, 0, 0, 0},
      {3.0 / 40, 9.0 / 40, 0, 0, 0},
      {44.0 / 45, -56.0 / 15, 32.0 / 9, 0, 0},
      {19372.0 / 6561, -25360.0 / 2187, 64448.0 / 6561, -212.0 / 729, 0},
      {9017.0 / 3168, -355.0 / 33, 46732.0 / 5247, 49.0 / 176,
       -5103.0 / 18656},
  };
  static const double Bb[6] = {35.0 / 384,  0,              500.0 / 1113,
                               125.0 / 192, -2187.0 / 6784, 11.0 / 84};

  const float hb1 = (float)(hh * Bb[0]);
  const float hb2 = (float)(hh * Bb[1]);
  const float hb3 = (float)(hh * Bb[2]);
  const float hb4 = (float)(hh * Bb[3]);
  const float hb5 = (float)(hh * Bb[4]);
  const float hb6 = (float)(hh * Bb[5]);

  for (int d = 0; d < DEPTH; ++d) {
    const float* W1d = W1 + (size_t)d * LOOK * HID;
    const float* b1d = b1 + (size_t)d * HID;
    const float* W2d = W2 + (size_t)d * HID * HID;
    const float* b2d = b2 + (size_t)d * HID;
    const float* W3d = W3 + (size_t)d * HID * LOOK;
    const float* b3d = b3 + (size_t)d * LOOK;

    k_w2split<<<dim3(16, 16), 256, 0, stream>>>(W2d, W2Th, W2Tl);
    k_w1t<<<dim3(128), 256, 0, stream>>>(W1d, W1Th, W1Tl);
    k_w3t<<<dim3(128), 256, 0, stream>>>(W3d, W3Th, W3Tl);

    for (int s = 0; s < NSTEPS; ++s) {
      for (int st = 0; st < 6; ++st) {
        float pv[5] = {0.f, 0.f, 0.f, 0.f, 0.f};
        float pc = 0.f;
        if (st < 5) {
          for (int jj = 0; jj < 5; ++jj)
            if (jj < st) pv[jj] = (float)(hh * A[st + 1][jj]);
          pc = (float)(hh * A[st + 1][st]);
        }
        k_l1<<<dim3(BATCH / 128, HID / 256), 512, 0, stream>>>(
            zh, zl, W1Th, W1Tl, b1d, H1h, H1l);
        k_mid<<<dim3(256), 512, 0, stream>>>(H1h, H1l, W2Th, W2Tl, b2d, H2h,
                                             H2l);
        const int comb = (st == 5) ? 1 : 0;
        float* kout = (st < 5) ? kk[st] : kk[0];
        k_l3<<<dim3(BATCH / 32), 256, 0, stream>>>(
            H2h, H2l, W3Th, W3Tl, b3d, kout, kk[0], kk[1], kk[2], kk[3],
            kk[4], y, zh, zl, comb, pv[0], pv[1], pv[2], pv[3], pv[4], pc,
            hb1, hb2, hb3, hb4, hb5, hb6);
      }
    }
  }

  k_readout<<<dim3(BATCH / 256), 256, 0, stream>>>(y, Wf, bf, out);
}